// Round 1
// baseline (730.568 us; speedup 1.0000x reference)
//
#include <hip/hip_runtime.h>
#include <math.h>

#define NPIX 4096   // 64*64
#define WID 64
#define DIMC 48
#define NB 2

// ---------------- LN over channels + 1x1 conv ----------------
// grid: (64 pixel-tiles, 4 o-groups, NB batches), block 64
__global__ void k_ln_conv(const float* __restrict__ x,
                          const float* __restrict__ lw, const float* __restrict__ lb,
                          const float* __restrict__ cw, const float* __restrict__ cb,
                          float* __restrict__ out, int OC) {
    int p = blockIdx.x * 64 + threadIdx.x;
    int og = blockIdx.y;
    int b = blockIdx.z;
    const float* xb = x + (size_t)b * DIMC * NPIX;
    float v[DIMC];
    float mu = 0.f;
#pragma unroll
    for (int c = 0; c < DIMC; c++) { v[c] = xb[(size_t)c * NPIX + p]; mu += v[c]; }
    mu *= (1.f / DIMC);
    float var = 0.f;
#pragma unroll
    for (int c = 0; c < DIMC; c++) { float d = v[c] - mu; var += d * d; }
    var *= (1.f / DIMC);
    float rs = rsqrtf(var + 1e-5f);
#pragma unroll
    for (int c = 0; c < DIMC; c++) v[c] = (v[c] - mu) * rs * lw[c] + lb[c];
    int chunk = OC >> 2;
    int o0 = og * chunk;
    for (int o = o0; o < o0 + chunk; o++) {
        float acc = cb[o];
        const float* wrow = cw + (size_t)o * DIMC;
#pragma unroll
        for (int c = 0; c < DIMC; c++) acc += wrow[c] * v[c];
        out[((size_t)b * OC + o) * NPIX + p] = acc;
    }
}

// ---------------- depthwise 3x3, SAME ----------------
__global__ void k_dw3(const float* __restrict__ in, const float* __restrict__ w,
                      const float* __restrict__ bias, float* __restrict__ out, int C) {
    int idx = blockIdx.x * 256 + threadIdx.x;
    int total = NB * C * NPIX;
    if (idx >= total) return;
    int xx = idx & 63;
    int yy = (idx >> 6) & 63;
    int bc = idx >> 12;          // b*C + c
    int c = bc % C;
    const float* ip = in + (size_t)bc * NPIX;
    const float* wp = w + (size_t)c * 9;
    float acc = bias[c];
#pragma unroll
    for (int ky = 0; ky < 3; ky++) {
        int y2 = yy + ky - 1;
        if ((unsigned)y2 < 64u) {
#pragma unroll
            for (int kx = 0; kx < 3; kx++) {
                int x2 = xx + kx - 1;
                if ((unsigned)x2 < 64u) acc += ip[y2 * 64 + x2] * wp[ky * 3 + kx];
            }
        }
    }
    out[idx] = acc;
}

// ---------------- split to heads, l2norm q,k, fold temperature ----------------
// grid: (64 tiles, 2 heads, NB), block 64
__global__ void k_heads(const float* __restrict__ qkv, const float* __restrict__ temp,
                        float* __restrict__ Q, float* __restrict__ K, float* __restrict__ V) {
    int n = blockIdx.x * 64 + threadIdx.x;
    int h = blockIdx.y;
    int b = blockIdx.z;
    const float* base = qkv + (size_t)b * 144 * NPIX;
    float q[24], k[24], vv[24];
    float sq = 0.f, sk = 0.f;
#pragma unroll
    for (int cc = 0; cc < 24; cc++) {
        q[cc] = base[(size_t)(h * 24 + cc) * NPIX + n];       sq += q[cc] * q[cc];
        k[cc] = base[(size_t)(48 + h * 24 + cc) * NPIX + n];  sk += k[cc] * k[cc];
        vv[cc] = base[(size_t)(96 + h * 24 + cc) * NPIX + n];
    }
    float rq = temp[h] / fmaxf(sqrtf(sq), 1e-12f);
    float rk = 1.f / fmaxf(sqrtf(sk), 1e-12f);
    size_t o = ((size_t)(b * 2 + h) * NPIX + n) * 24;
#pragma unroll
    for (int cc = 0; cc < 24; cc++) {
        Q[o + cc] = q[cc] * rq;
        K[o + cc] = k[cc] * rk;
        V[o + cc] = vv[cc];
    }
}

// ---------------- flash-style attention (no max needed: |score|<=temp) ----------------
// grid: (64 q-tiles, 4 bh), block 256
__global__ __launch_bounds__(256) void k_attn(const float* __restrict__ Q,
                                              const float* __restrict__ K,
                                              const float* __restrict__ V,
                                              float* __restrict__ O) {
    int qt = blockIdx.x;
    int bh = blockIdx.y;
    int t = threadIdx.x;
    int r = t & 63;      // query row within tile
    int g = t >> 6;      // 0..3
    int c0 = g * 6;

    __shared__ float Kt[64 * 25];
    __shared__ float Vt[64 * 25];
    __shared__ float S[64 * 65];
    __shared__ float lsum[64];

    const float* Qb = Q + ((size_t)bh * NPIX + (size_t)qt * 64) * 24;
    float q[24];
#pragma unroll
    for (int d = 0; d < 24; d++) q[d] = Qb[r * 24 + d];
    float o[6] = {0.f, 0.f, 0.f, 0.f, 0.f, 0.f};
    if (t < 64) lsum[t] = 0.f;

    for (int kt = 0; kt < 64; kt++) {
        const float* Kb = K + ((size_t)bh * NPIX + (size_t)kt * 64) * 24;
        const float* Vb = V + ((size_t)bh * NPIX + (size_t)kt * 64) * 24;
        __syncthreads();   // prior-iter readers of Kt/Vt/S done
        for (int i = t; i < 1536; i += 256) {
            int row = i / 24, d = i - row * 24;
            Kt[row * 25 + d] = Kb[i];
            Vt[row * 25 + d] = Vb[i];
        }
        __syncthreads();
        // scores + exp (scores bounded by |temperature| since q,k unit-norm)
#pragma unroll
        for (int jj = 0; jj < 16; jj++) {
            int j = g * 16 + jj;
            float acc = 0.f;
#pragma unroll
            for (int d = 0; d < 24; d++) acc += q[d] * Kt[j * 25 + d];
            S[r * 65 + j] = __expf(acc);
        }
        __syncthreads();
        if (t < 64) {
            float s = 0.f;
            for (int j = 0; j < 64; j++) s += S[t * 65 + j];
            lsum[t] += s;
        }
        for (int j = 0; j < 64; j++) {
            float p = S[r * 65 + j];
#pragma unroll
            for (int c = 0; c < 6; c++) o[c] += p * Vt[j * 25 + c0 + c];
        }
    }
    __syncthreads();
    float rl = 1.f / lsum[r];
    int b = bh >> 1, h = bh & 1;
    int n = qt * 64 + r;
#pragma unroll
    for (int c = 0; c < 6; c++)
        O[((size_t)b * DIMC + h * 24 + c0 + c) * NPIX + n] = o[c] * rl;
}

// ---------------- 1x1 proj + residual ----------------
// grid: (64 tiles, NB), block 64
__global__ void k_proj(const float* __restrict__ x, const float* __restrict__ O,
                       const float* __restrict__ w, const float* __restrict__ bias,
                       float* __restrict__ x1) {
    int p = blockIdx.x * 64 + threadIdx.x;
    int b = blockIdx.y;
    float v[48];
#pragma unroll
    for (int i = 0; i < 48; i++) v[i] = O[((size_t)b * 48 + i) * NPIX + p];
    for (int o = 0; o < 48; o++) {
        float acc = bias[o];
        const float* wrow = w + (size_t)o * 48;
#pragma unroll
        for (int i = 0; i < 48; i++) acc += wrow[i] * v[i];
        size_t idx = ((size_t)b * 48 + o) * NPIX + p;
        x1[idx] = x[idx] + acc;
    }
}

// ---------------- exact GELU gate ----------------
__global__ void k_gate(const float* __restrict__ f, float* __restrict__ y) {
    int idx = blockIdx.x * 256 + threadIdx.x;
    int total = NB * 96 * NPIX;
    if (idx >= total) return;
    int b = idx / (96 * NPIX);
    int rem = idx - b * 96 * NPIX;
    float a = f[(size_t)b * 192 * NPIX + rem];
    float gte = f[(size_t)b * 192 * NPIX + 96 * NPIX + rem];
    float ge = 0.5f * a * (1.f + erff(a * 0.70710678118654752f));
    y[idx] = ge * gte;
}

// ---------------- 1x1 fo + residual ----------------
// grid: (64 tiles, NB), block 64
__global__ void k_fo(const float* __restrict__ x1, const float* __restrict__ y,
                     const float* __restrict__ w, const float* __restrict__ bias,
                     float* __restrict__ out) {
    int p = blockIdx.x * 64 + threadIdx.x;
    int b = blockIdx.y;
    float v[96];
#pragma unroll
    for (int i = 0; i < 96; i++) v[i] = y[((size_t)b * 96 + i) * NPIX + p];
    for (int o = 0; o < 48; o++) {
        float acc = bias[o];
        const float* wrow = w + (size_t)o * 96;
#pragma unroll
        for (int i = 0; i < 96; i++) acc += wrow[i] * v[i];
        size_t idx = ((size_t)b * 48 + o) * NPIX + p;
        out[idx] = x1[idx] + acc;
    }
}

extern "C" void kernel_launch(void* const* d_in, const int* in_sizes, int n_in,
                              void* d_out, int out_size, void* d_ws, size_t ws_size,
                              hipStream_t stream) {
    const float* x       = (const float*)d_in[0];
    const float* n1w     = (const float*)d_in[1];
    const float* n1b     = (const float*)d_in[2];
    const float* qkv_w   = (const float*)d_in[3];
    const float* qkv_b   = (const float*)d_in[4];
    const float* qkvdw_w = (const float*)d_in[5];
    const float* qkvdw_b = (const float*)d_in[6];
    const float* temp    = (const float*)d_in[7];
    const float* proj_w  = (const float*)d_in[8];
    const float* proj_b  = (const float*)d_in[9];
    const float* n2w     = (const float*)d_in[10];
    const float* n2b     = (const float*)d_in[11];
    const float* fi_w    = (const float*)d_in[12];
    const float* fi_b    = (const float*)d_in[13];
    const float* fdw_w   = (const float*)d_in[14];
    const float* fdw_b   = (const float*)d_in[15];
    const float* fo_w    = (const float*)d_in[16];
    const float* fo_b    = (const float*)d_in[17];

    float* ws = (float*)d_ws;
    // workspace layout (floats)
    float* qkv_pre = ws;                        // 2*144*4096 = 1179648
    float* qkv     = qkv_pre + 1179648;         // 1179648
    float* Q       = qkv + 1179648;             // 393216
    float* K       = Q + 393216;                // 393216
    float* V       = K + 393216;                // 393216
    float* O       = V + 393216;                // 393216
    float* x1      = O + 393216;                // 393216
    float* f_pre   = x1 + 393216;               // 1572864
    float* f       = f_pre + 1572864;           // 1572864
    float* y       = f + 1572864;               // 786432

    // attention branch
    {
        dim3 g(64, 4, NB);
        k_ln_conv<<<g, 64, 0, stream>>>(x, n1w, n1b, qkv_w, qkv_b, qkv_pre, 144);
    }
    {
        int total = NB * 144 * NPIX;
        k_dw3<<<(total + 255) / 256, 256, 0, stream>>>(qkv_pre, qkvdw_w, qkvdw_b, qkv, 144);
    }
    {
        dim3 g(64, 2, NB);
        k_heads<<<g, 64, 0, stream>>>(qkv, temp, Q, K, V);
    }
    {
        dim3 g(64, 4);
        k_attn<<<g, 256, 0, stream>>>(Q, K, V, O);
    }
    {
        dim3 g(64, NB);
        k_proj<<<g, 64, 0, stream>>>(x, O, proj_w, proj_b, x1);
    }
    // ffn branch
    {
        dim3 g(64, 4, NB);
        k_ln_conv<<<g, 64, 0, stream>>>(x1, n2w, n2b, fi_w, fi_b, f_pre, 192);
    }
    {
        int total = NB * 192 * NPIX;
        k_dw3<<<(total + 255) / 256, 256, 0, stream>>>(f_pre, fdw_w, fdw_b, f, 192);
    }
    {
        int total = NB * 96 * NPIX;
        k_gate<<<(total + 255) / 256, 256, 0, stream>>>(f, y);
    }
    {
        dim3 g(64, NB);
        k_fo<<<g, 64, 0, stream>>>(x1, y, fo_w, fo_b, (float*)d_out);
    }
}

// Round 2
// 244.318 us; speedup vs baseline: 2.9902x; 2.9902x over previous
//
#include <hip/hip_runtime.h>
#include <math.h>

#define NPIX 4096   // 64*64
#define DIMC 48
#define NB 2

typedef __attribute__((ext_vector_type(8))) short short8;
typedef __attribute__((ext_vector_type(4))) float floatx4;

static __device__ inline short f2bf(float f) {
    union { float f; unsigned u; } v; v.f = f;
    unsigned r = (v.u + 0x7FFFu + ((v.u >> 16) & 1u)) >> 16;
    return (short)r;
}

// ---------------- LN over channels + 1x1 conv ----------------
// grid: (64 pixel-tiles, OGROUPS, NB), block 64
__global__ void k_ln_conv(const float* __restrict__ x,
                          const float* __restrict__ lw, const float* __restrict__ lb,
                          const float* __restrict__ cw, const float* __restrict__ cb,
                          float* __restrict__ out, int OC) {
    int p = blockIdx.x * 64 + threadIdx.x;
    int og = blockIdx.y;
    int b = blockIdx.z;
    const float* xb = x + (size_t)b * DIMC * NPIX;
    float v[DIMC];
    float mu = 0.f;
#pragma unroll
    for (int c = 0; c < DIMC; c++) { v[c] = xb[(size_t)c * NPIX + p]; mu += v[c]; }
    mu *= (1.f / DIMC);
    float var = 0.f;
#pragma unroll
    for (int c = 0; c < DIMC; c++) { float d = v[c] - mu; var += d * d; }
    var *= (1.f / DIMC);
    float rs = rsqrtf(var + 1e-5f);
#pragma unroll
    for (int c = 0; c < DIMC; c++) v[c] = (v[c] - mu) * rs * lw[c] + lb[c];
    int chunk = OC / gridDim.y;
    int o0 = og * chunk;
    for (int o = o0; o < o0 + chunk; o++) {
        float acc = cb[o];
        const float* wrow = cw + (size_t)o * DIMC;
#pragma unroll
        for (int c = 0; c < DIMC; c++) acc += wrow[c] * v[c];
        out[((size_t)b * OC + o) * NPIX + p] = acc;
    }
}

// ---------------- depthwise 3x3, SAME ----------------
__global__ void k_dw3(const float* __restrict__ in, const float* __restrict__ w,
                      const float* __restrict__ bias, float* __restrict__ out, int C) {
    int idx = blockIdx.x * 256 + threadIdx.x;
    int total = NB * C * NPIX;
    if (idx >= total) return;
    int xx = idx & 63;
    int yy = (idx >> 6) & 63;
    int bc = idx >> 12;          // b*C + c
    int c = bc % C;
    const float* ip = in + (size_t)bc * NPIX;
    const float* wp = w + (size_t)c * 9;
    float acc = bias[c];
#pragma unroll
    for (int ky = 0; ky < 3; ky++) {
        int y2 = yy + ky - 1;
        if ((unsigned)y2 < 64u) {
#pragma unroll
            for (int kx = 0; kx < 3; kx++) {
                int x2 = xx + kx - 1;
                if ((unsigned)x2 < 64u) acc += ip[y2 * 64 + x2] * wp[ky * 3 + kx];
            }
        }
    }
    out[idx] = acc;
}

// ---------------- split heads, l2norm q,k (fold temp), emit bf16 MFMA layouts --------
// Qbf,Kbf: [bh][4096][32] row-major (d padded 24->32 with zeros)
// Vbf:     [bh][32][4096] channel-major (channels 24..31 zero)
// grid: (64, 2, NB), block 64
__global__ void k_heads(const float* __restrict__ qkv, const float* __restrict__ temp,
                        short* __restrict__ Qbf, short* __restrict__ Kbf,
                        short* __restrict__ Vbf) {
    int n = blockIdx.x * 64 + threadIdx.x;
    int h = blockIdx.y;
    int b = blockIdx.z;
    int bh = b * 2 + h;
    const float* base = qkv + (size_t)b * 144 * NPIX;
    float q[24], k[24], vv[24];
    float sq = 0.f, sk = 0.f;
#pragma unroll
    for (int c = 0; c < 24; c++) {
        q[c] = base[(size_t)(h * 24 + c) * NPIX + n];       sq += q[c] * q[c];
        k[c] = base[(size_t)(48 + h * 24 + c) * NPIX + n];  sk += k[c] * k[c];
        vv[c] = base[(size_t)(96 + h * 24 + c) * NPIX + n];
    }
    float rq = temp[h] / fmaxf(sqrtf(sq), 1e-12f);
    float rk = 1.f / fmaxf(sqrtf(sk), 1e-12f);
    size_t ro = ((size_t)bh * NPIX + n) * 32;
#pragma unroll
    for (int c = 0; c < 24; c++) {
        Qbf[ro + c] = f2bf(q[c] * rq);
        Kbf[ro + c] = f2bf(k[c] * rk);
    }
#pragma unroll
    for (int c = 24; c < 32; c++) { Qbf[ro + c] = 0; Kbf[ro + c] = 0; }
#pragma unroll
    for (int c = 0; c < 24; c++)
        Vbf[((size_t)bh * 32 + c) * NPIX + n] = f2bf(vv[c]);
#pragma unroll
    for (int c = 24; c < 32; c++)
        Vbf[((size_t)bh * 32 + c) * NPIX + n] = 0;
}

// ---------------- MFMA flash attention, key-split x4 ----------------
// grid: (qt=64, split=4, bh=4), block 256 (4 waves; wave w owns q-rows qt*64+w*16..+15)
// No softmax max needed: q,k unit-norm, |score| <= temp. Partials are linear in split.
// Opart: [bh][4][4096][32] fp32 (unnormalized), lpart: [bh][4][4096]
__global__ __launch_bounds__(256) void k_attn_mfma(const short* __restrict__ Qbf,
                                                   const short* __restrict__ Kbf,
                                                   const short* __restrict__ Vbf,
                                                   float* __restrict__ Opart,
                                                   float* __restrict__ lpart) {
    int qt = blockIdx.x;
    int s  = blockIdx.y;
    int bh = blockIdx.z;
    int t = threadIdx.x;
    int w = t >> 6;
    int lane = t & 63;
    int l15 = lane & 15;
    int quad = lane >> 4;

    __shared__ float P[4][16][36];   // per-wave P tile, stride 36 (16B-aligned rows)

    int qrow0 = qt * 64 + w * 16;
    // A-frag (Q): A[m=l15][k=quad*8+j]
    const short* qptr = Qbf + ((size_t)(bh * NPIX + qrow0 + l15)) * 32 + quad * 8;
    short8 aq = *(const short8*)qptr;

    floatx4 zf = {0.f, 0.f, 0.f, 0.f};
    floatx4 o0 = zf, o1 = zf;
    float ls[4] = {0.f, 0.f, 0.f, 0.f};

    int key0 = s * 1024;
    for (int kt = 0; kt < 32; kt++) {
        int kb = key0 + kt * 32;
        // scores for 32 keys (2 col-tiles of 16): B[k=d][n=key] = Kbf[key][d]
        const short* kp0 = Kbf + ((size_t)(bh * NPIX + kb + l15)) * 32 + quad * 8;
        short8 b0 = *(const short8*)kp0;
        short8 b1 = *(const short8*)(kp0 + 16 * 32);
        floatx4 s0 = __builtin_amdgcn_mfma_f32_16x16x32_bf16(aq, b0, zf, 0, 0, 0);
        floatx4 s1 = __builtin_amdgcn_mfma_f32_16x16x32_bf16(aq, b1, zf, 0, 0, 0);
        // exp in C-layout: col=l15, row=quad*4+r. Accumulate per-lane row-sum partials.
#pragma unroll
        for (int r = 0; r < 4; r++) {
            float p0 = __expf(s0[r]);
            float p1 = __expf(s1[r]);
            ls[r] += p0 + p1;
            P[w][quad * 4 + r][l15]      = p0;
            P[w][quad * 4 + r][16 + l15] = p1;
        }
        // C-layout -> A-layout via per-wave LDS (no barrier: same wave)
        short8 ap;
#pragma unroll
        for (int j = 0; j < 8; j++) ap[j] = f2bf(P[w][l15][quad * 8 + j]);
        // PV: B[k=key][n=ch] = Vbf[ch][key]
        const short* vp0 = Vbf + ((size_t)(bh * 32 + l15)) * NPIX + kb + quad * 8;
        short8 vb0 = *(const short8*)vp0;
        short8 vb1 = *(const short8*)(vp0 + 16 * NPIX);
        o0 = __builtin_amdgcn_mfma_f32_16x16x32_bf16(ap, vb0, o0, 0, 0, 0);
        o1 = __builtin_amdgcn_mfma_f32_16x16x32_bf16(ap, vb1, o1, 0, 0, 0);
    }
    // full row sums across the 16 lanes of each quad
#pragma unroll
    for (int m = 1; m < 16; m <<= 1) {
#pragma unroll
        for (int r = 0; r < 4; r++) ls[r] += __shfl_xor(ls[r], m, 64);
    }
#pragma unroll
    for (int r = 0; r < 4; r++) {
        int n = qrow0 + quad * 4 + r;
        size_t oi = (((size_t)(bh * 4 + s) * NPIX) + n) * 32;
        Opart[oi + l15] = o0[r];
        Opart[oi + 16 + l15] = o1[r];
        if (l15 == 0) lpart[((size_t)(bh * 4 + s)) * NPIX + n] = ls[r];
    }
}

// ---------------- combine split partials, normalize, write O in [b][c][n] ----------
// grid: 64 blocks x 256 (thread = bh*4096+n)
__global__ void k_attn_reduce(const float* __restrict__ Opart,
                              const float* __restrict__ lpart,
                              float* __restrict__ O) {
    int idx = blockIdx.x * 256 + threadIdx.x;
    int bh = idx >> 12, n = idx & 4095;
    float l = 0.f;
#pragma unroll
    for (int s = 0; s < 4; s++) l += lpart[((size_t)(bh * 4 + s)) * NPIX + n];
    float rl = 1.f / l;
    int b = bh >> 1, h = bh & 1;
#pragma unroll
    for (int c = 0; c < 24; c++) {
        float acc = 0.f;
#pragma unroll
        for (int s = 0; s < 4; s++)
            acc += Opart[(((size_t)(bh * 4 + s) * NPIX) + n) * 32 + c];
        O[((size_t)b * DIMC + h * 24 + c) * NPIX + n] = acc * rl;
    }
}

// ---------------- 1x1 proj + residual ----------------
// grid: (64 tiles, NB, 6 ogroups), block 64
__global__ void k_proj(const float* __restrict__ x, const float* __restrict__ O,
                       const float* __restrict__ w, const float* __restrict__ bias,
                       float* __restrict__ x1) {
    int p = blockIdx.x * 64 + threadIdx.x;
    int b = blockIdx.y;
    int o0 = blockIdx.z * 8;
    float v[48];
#pragma unroll
    for (int i = 0; i < 48; i++) v[i] = O[((size_t)b * 48 + i) * NPIX + p];
    for (int o = o0; o < o0 + 8; o++) {
        float acc = bias[o];
        const float* wrow = w + (size_t)o * 48;
#pragma unroll
        for (int i = 0; i < 48; i++) acc += wrow[i] * v[i];
        size_t idx = ((size_t)b * 48 + o) * NPIX + p;
        x1[idx] = x[idx] + acc;
    }
}

// ---------------- exact GELU gate ----------------
__global__ void k_gate(const float* __restrict__ f, float* __restrict__ y) {
    int idx = blockIdx.x * 256 + threadIdx.x;
    int total = NB * 96 * NPIX;
    if (idx >= total) return;
    int b = idx / (96 * NPIX);
    int rem = idx - b * 96 * NPIX;
    float a = f[(size_t)b * 192 * NPIX + rem];
    float gte = f[(size_t)b * 192 * NPIX + 96 * NPIX + rem];
    float ge = 0.5f * a * (1.f + erff(a * 0.70710678118654752f));
    y[idx] = ge * gte;
}

// ---------------- 1x1 fo + residual ----------------
// grid: (64 tiles, NB, 6 ogroups), block 64
__global__ void k_fo(const float* __restrict__ x1, const float* __restrict__ y,
                     const float* __restrict__ w, const float* __restrict__ bias,
                     float* __restrict__ out) {
    int p = blockIdx.x * 64 + threadIdx.x;
    int b = blockIdx.y;
    int o0 = blockIdx.z * 8;
    float v[96];
#pragma unroll
    for (int i = 0; i < 96; i++) v[i] = y[((size_t)b * 96 + i) * NPIX + p];
    for (int o = o0; o < o0 + 8; o++) {
        float acc = bias[o];
        const float* wrow = w + (size_t)o * 96;
#pragma unroll
        for (int i = 0; i < 96; i++) acc += wrow[i] * v[i];
        size_t idx = ((size_t)b * 48 + o) * NPIX + p;
        out[idx] = x1[idx] + acc;
    }
}

extern "C" void kernel_launch(void* const* d_in, const int* in_sizes, int n_in,
                              void* d_out, int out_size, void* d_ws, size_t ws_size,
                              hipStream_t stream) {
    const float* x       = (const float*)d_in[0];
    const float* n1w     = (const float*)d_in[1];
    const float* n1b     = (const float*)d_in[2];
    const float* qkv_w   = (const float*)d_in[3];
    const float* qkv_b   = (const float*)d_in[4];
    const float* qkvdw_w = (const float*)d_in[5];
    const float* qkvdw_b = (const float*)d_in[6];
    const float* temp    = (const float*)d_in[7];
    const float* proj_w  = (const float*)d_in[8];
    const float* proj_b  = (const float*)d_in[9];
    const float* n2w     = (const float*)d_in[10];
    const float* n2b     = (const float*)d_in[11];
    const float* fi_w    = (const float*)d_in[12];
    const float* fi_b    = (const float*)d_in[13];
    const float* fdw_w   = (const float*)d_in[14];
    const float* fdw_b   = (const float*)d_in[15];
    const float* fo_w    = (const float*)d_in[16];
    const float* fo_b    = (const float*)d_in[17];

    float* ws = (float*)d_ws;
    // workspace layout (float units). Opart/lpart alias qkv_pre+qkv (dead by then).
    float* qkv_pre = ws;                        // 1179648 f
    float* qkv     = qkv_pre + 1179648;         // 1179648 f
    float* Opart   = qkv_pre;                   // 2097152 f (alias, used after k_heads)
    float* lpart   = qkv_pre + 2097152;         // 65536 f (fits in qkv_pre+qkv = 2359296)
    float* base2   = qkv + 1179648;
    short* Qbf     = (short*)base2;             // 524288 s = 262144 f
    short* Kbf     = Qbf + 524288;              // 524288 s
    short* Vbf     = Kbf + 524288;              // 524288 s
    float* O       = base2 + 786432;            // 393216 f
    float* x1      = O + 393216;                // 393216 f
    float* f_pre   = x1 + 393216;               // 1572864 f
    float* f       = f_pre + 1572864;           // 1572864 f
    float* y       = f + 1572864;               // 786432 f

    // ---- attention branch ----
    {
        dim3 g(64, 12, NB);
        k_ln_conv<<<g, 64, 0, stream>>>(x, n1w, n1b, qkv_w, qkv_b, qkv_pre, 144);
    }
    {
        int total = NB * 144 * NPIX;
        k_dw3<<<(total + 255) / 256, 256, 0, stream>>>(qkv_pre, qkvdw_w, qkvdw_b, qkv, 144);
    }
    {
        dim3 g(64, 2, NB);
        k_heads<<<g, 64, 0, stream>>>(qkv, temp, Qbf, Kbf, Vbf);
    }
    {
        dim3 g(64, 4, 4);
        k_attn_mfma<<<g, 256, 0, stream>>>(Qbf, Kbf, Vbf, Opart, lpart);
    }
    {
        k_attn_reduce<<<64, 256, 0, stream>>>(Opart, lpart, O);
    }
    {
        dim3 g(64, NB, 6);
        k_proj<<<g, 64, 0, stream>>>(x, O, proj_w, proj_b, x1);
    }
    // ---- ffn branch ----
    {
        dim3 g(64, 12, NB);
        k_ln_conv<<<g, 64, 0, stream>>>(x1, n2w, n2b, fi_w, fi_b, f_pre, 192);
    }
    {
        int total = NB * 192 * NPIX;
        k_dw3<<<(total + 255) / 256, 256, 0, stream>>>(f_pre, fdw_w, fdw_b, f, 192);
    }
    {
        int total = NB * 96 * NPIX;
        k_gate<<<(total + 255) / 256, 256, 0, stream>>>(f, y);
    }
    {
        dim3 g(64, NB, 6);
        k_fo<<<g, 64, 0, stream>>>(x1, y, fo_w, fo_b, (float*)d_out);
    }
}